// Round 6
// baseline (245.627 us; speedup 1.0000x reference)
//
#include <hip/hip_runtime.h>
#include <hip/hip_bf16.h>

#define B_ 256
#define S_ 256
#define T_ 128
#define START_ 126
#define STOP_ 127
#define NSEQ 16
#define NBLK (B_ / NSEQ)      // 16 blocks
#define LDS_K 136             // 128 + 8 bf16 pad (bank de-phase)

typedef __attribute__((ext_vector_type(8))) short short8;
typedef __attribute__((ext_vector_type(4))) float f32x4;

// float -> bf16 bits, round-to-nearest-even
__device__ __forceinline__ unsigned short f2bf(float f) {
    unsigned u = __float_as_uint(f);
    return (unsigned short)((u + 0x7FFFu + ((u >> 16) & 1u)) >> 16);
}
__device__ __forceinline__ unsigned cvt_pk(float lo, float hi) {
    unsigned r;
    asm("v_cvt_pk_bf16_f32 %0, %1, %2" : "=v"(r) : "v"(lo), "v"(hi));
    return r;
}

// 16 sequences per block (one per MFMA B-column), 4 waves.
// Wave W owns output tags [32W, 32W+32) = rt-tiles {2W, 2W+1}: 8 MFMAs/step
// on its own SIMD -> all 4 matrix pipes busy, zero broadcast waste.
// State exchange: dbuf LDS [seq][k] bf16; ONE raw s_barrier per step
// (lgkmcnt-only drain -- global feat prefetch stays in flight).
// Shared A/B k-map kappa(g,e) = 8g+e  (shared-kappa principle HW-validated
// rounds 1/4: any per-tile bijection used by BOTH operands cancels).
__global__ __launch_bounds__(256, 1) void crf_fwd(
    const float* __restrict__ feats,      // [B, S, T]
    const float* __restrict__ trans,      // [T, T]
    const int*   __restrict__ tags,       // [B, S]
    const int*   __restrict__ mask,       // [B, S]
    float* __restrict__ out)              // [1]
{
    const int tid = threadIdx.x;
    const int W = tid >> 6, l = tid & 63, g = l >> 4, c = l & 15;
    const int blk = blockIdx.x;
    const int seq = blk * NSEQ + c;       // this lane's sequence (column c)
    const float* fb = feats + (size_t)seq * (S_ * T_);

    __shared__ __align__(16) unsigned short st[2][NSEQ][LDS_K];
    __shared__ float scl[NSEQ];
    __shared__ float wred[4][NSEQ];
    __shared__ int   lens[NSEQ];

    // ---- A fragments (constant, 32 VGPRs): A-row=c, k = 32kt+8g+e ----
    short8 af[2][4];                      // [rt][kt]
    #pragma unroll
    for (int rt = 0; rt < 2; ++rt) {
        #pragma unroll
        for (int kt = 0; kt < 4; ++kt) {
            short8 f;
            #pragma unroll
            for (int e = 0; e < 8; ++e)
                f[e] = (short)f2bf(__expf(
                    trans[(32 * kt + 8 * g + e) * T_ + 32 * W + 16 * rt + c]));
            af[rt][kt] = f;
        }
    }

    // ---- per-seq lengths (prefix mask) ----
    {
        const int* mrow = mask + seq * S_ + (4 * W + g) * 16;
        int p = 0;
        #pragma unroll
        for (int i = 0; i < 4; ++i) {
            int4 m4 = *(const int4*)&mrow[4 * i];
            p += m4.x + m4.y + m4.z + m4.w;
        }
        p += __shfl_xor(p, 16, 64);
        p += __shfl_xor(p, 32, 64);       // sum over g: per-(W,c) 64-pos count
        if (g == 0) wred[W][c] = (float)p;
    }
    __syncthreads();
    const int len_c = (int)(wred[0][c] + wred[1][c] + wred[2][c] + wred[3][c]);
    if (W == 0 && g == 0) lens[c] = len_c;
    int lm = len_c;
    #pragma unroll
    for (int o = 1; o < 16; o <<= 1) lm = max(lm, __shfl_xor(lm, o, 64));

    // ---- init state t=0 + STOP factors ----
    float held[2][4], ets[2][4], M = 0.f;
    #pragma unroll
    for (int rt = 0; rt < 2; ++rt) {
        #pragma unroll
        for (int q = 0; q < 4; ++q) {
            const int j = 32 * W + 16 * rt + 4 * g + q;
            held[rt][q] = __expf(fb[j] + trans[START_ * T_ + j]);
            ets[rt][q]  = __expf(trans[j * T_ + STOP_]);
        }
    }
    #pragma unroll
    for (int rt = 0; rt < 2; ++rt) {
        const unsigned r0 = cvt_pk(held[rt][0], held[rt][1]);
        const unsigned r1 = cvt_pk(held[rt][2], held[rt][3]);
        *(uint2*)&st[0][c][32 * W + 16 * rt + 4 * g] = make_uint2(r0, r1);
    }

    // depth-2 feat prefetch: efO for odd t, efE for even t (static parity split)
    float efO[2][4], efE[2][4];
    #pragma unroll
    for (int rt = 0; rt < 2; ++rt) {
        #pragma unroll
        for (int q = 0; q < 4; ++q) {
            const int j = 32 * W + 16 * rt + 4 * g + q;
            efO[rt][q] = fb[1 * T_ + j];
            efE[rt][q] = fb[2 * T_ + j];
        }
    }
    __syncthreads();                      // state0 + lens visible

    // ---- main recurrence: state t from state t-1 ----
    for (int t = 1; t < lm; ++t) {
        const int p = (t - 1) & 1;
        // B fragments of state t-1 (4 x ds_read_b128, issued first)
        const short8 bf0 = *(const short8*)&st[p][c][ 0 + 8 * g];
        const short8 bf1 = *(const short8*)&st[p][c][32 + 8 * g];
        const short8 bf2 = *(const short8*)&st[p][c][64 + 8 * g];
        const short8 bf3 = *(const short8*)&st[p][c][96 + 8 * g];
        float sc = 1.0f;
        if ((t & 3) == 0) sc = scl[c];    // written at t-1, pre-barrier

        // consume prefetched feats (fills LDS latency window) + reload depth-2
        float fe[2][4];
        const int tn = (t + 2 < S_) ? t + 2 : S_ - 1;
        if (t & 1) {
            #pragma unroll
            for (int rt = 0; rt < 2; ++rt)
                #pragma unroll
                for (int q = 0; q < 4; ++q) {
                    fe[rt][q] = __expf(efO[rt][q]);
                    efO[rt][q] = fb[tn * T_ + 32 * W + 16 * rt + 4 * g + q];
                }
        } else {
            #pragma unroll
            for (int rt = 0; rt < 2; ++rt)
                #pragma unroll
                for (int q = 0; q < 4; ++q) {
                    fe[rt][q] = __expf(efE[rt][q]);
                    efE[rt][q] = fb[tn * T_ + 32 * W + 16 * rt + 4 * g + q];
                }
        }

        // 8 MFMAs: 2 chains (rt), kt-serial
        f32x4 a0 = {0.f, 0.f, 0.f, 0.f}, a1 = {0.f, 0.f, 0.f, 0.f};
        a0 = __builtin_amdgcn_mfma_f32_16x16x32_bf16(af[0][0], bf0, a0, 0, 0, 0);
        a1 = __builtin_amdgcn_mfma_f32_16x16x32_bf16(af[1][0], bf0, a1, 0, 0, 0);
        a0 = __builtin_amdgcn_mfma_f32_16x16x32_bf16(af[0][1], bf1, a0, 0, 0, 0);
        a1 = __builtin_amdgcn_mfma_f32_16x16x32_bf16(af[1][1], bf1, a1, 0, 0, 0);
        a0 = __builtin_amdgcn_mfma_f32_16x16x32_bf16(af[0][2], bf2, a0, 0, 0, 0);
        a1 = __builtin_amdgcn_mfma_f32_16x16x32_bf16(af[1][2], bf2, a1, 0, 0, 0);
        a0 = __builtin_amdgcn_mfma_f32_16x16x32_bf16(af[0][3], bf3, a0, 0, 0, 0);
        a1 = __builtin_amdgcn_mfma_f32_16x16x32_bf16(af[1][3], bf3, a1, 0, 0, 0);

        // per-seq freeze + emit multiply
        const bool act = (t < len_c);
        #pragma unroll
        for (int q = 0; q < 4; ++q) {
            held[0][q] = act ? a0[q] * fe[0][q] : held[0][q];
            held[1][q] = act ? a1[q] * fe[1][q] : held[1][q];
        }

        // renorm every 4 steps (stale-by-1 per-seq scale; frozen seqs scaled
        // too -- M accounts, cancels in fwd_c)
        if ((t & 3) == 0) {
            const float rs = __builtin_amdgcn_rcpf(sc);
            #pragma unroll
            for (int rt = 0; rt < 2; ++rt)
                #pragma unroll
                for (int q = 0; q < 4; ++q) held[rt][q] *= rs;
            M += __logf(sc);
        }
        // publish scale candidate for the NEXT renorm (u[tag 0][c])
        if ((t & 3) == 3 && W == 0 && g == 0) scl[c] = held[0][0];

        // write state t (2 x ds_write_b64)
        #pragma unroll
        for (int rt = 0; rt < 2; ++rt) {
            const unsigned r0 = cvt_pk(held[rt][0], held[rt][1]);
            const unsigned r1 = cvt_pk(held[rt][2], held[rt][3]);
            *(uint2*)&st[t & 1][c][32 * W + 16 * rt + 4 * g] = make_uint2(r0, r1);
        }
        // lgkm-only drain + raw barrier (global prefetch stays in flight)
        asm volatile("s_waitcnt lgkmcnt(0)\n\ts_barrier" ::: "memory");
    }

    // ---- forward score per seq: fwd_c = M_c + log(sum_j u_j * etsSTOP_j) ----
    float pv = 0.f;
    #pragma unroll
    for (int rt = 0; rt < 2; ++rt)
        #pragma unroll
        for (int q = 0; q < 4; ++q) pv += held[rt][q] * ets[rt][q];
    pv += __shfl_xor(pv, 16, 64);
    pv += __shfl_xor(pv, 32, 64);         // sum over g within wave
    if (g == 0) wred[W][c] = pv;
    __syncthreads();
    const float fwd_c =
        M + __logf(wred[0][c] + wred[1][c] + wred[2][c] + wred[3][c]);

    // ---- gold path score: thread tid = position s, loop over block's seqs ----
    float part = (W == 0 && g == 0) ? fwd_c : 0.f;  // count each fwd_c once
    const int s = tid;
    #pragma unroll 4
    for (int q2 = 0; q2 < NSEQ; ++q2) {
        const int sq = blk * NSEQ + q2;
        if (mask[sq * S_ + s]) {
            const int tg  = tags[sq * S_ + s];
            const int pvt = s ? tags[sq * S_ + s - 1] : START_;
            float e = feats[(size_t)sq * (S_ * T_) + s * T_ + tg]
                    + trans[pvt * T_ + tg];
            if (s == lens[q2] - 1) e += trans[tg * T_ + STOP_];
            part -= e;
        }
    }
    #pragma unroll
    for (int o = 32; o; o >>= 1) part += __shfl_down(part, o, 64);
    __syncthreads();
    if (l == 0) wred[0][W] = part;
    __syncthreads();
    if (tid == 0)
        atomicAdd(out, wred[0][0] + wred[0][1] + wred[0][2] + wred[0][3]);
}

extern "C" void kernel_launch(void* const* d_in, const int* in_sizes, int n_in,
                              void* d_out, int out_size, void* d_ws, size_t ws_size,
                              hipStream_t stream) {
    const float* feats = (const float*)d_in[0];
    const float* trans = (const float*)d_in[1];
    const int*   tags  = (const int*)d_in[2];
    const int*   mask  = (const int*)d_in[3];
    float* out = (float*)d_out;

    hipMemsetAsync(out, 0, sizeof(float), stream);
    crf_fwd<<<dim3(NBLK), dim3(256), 0, stream>>>(feats, trans, tags, mask, out);
}